// Round 1
// baseline (1369.290 us; speedup 1.0000x reference)
//
#include <hip/hip_runtime.h>
#include <math.h>

#define N_USERS 60000
#define N_ITEMS 30000
#define N_NODES 90000
#define DD 64
#define FF 192              // 3*DD
#define E_UND 500000
#define E_DIR 1000000
#define SCAN_NBLK 88        // ceil(90000/1024)

// ---------------- edge-layout probe: int32 vs int64 storage ----------------
// int64 values < 2^31 have zero high words; random int32 edge data at odd
// slots is essentially never all-zero across 256 samples.
__global__ void k_mode(const int* __restrict__ ei, int* __restrict__ mode) {
    __shared__ int any;
    if (threadIdx.x == 0) any = 0;
    __syncthreads();
    if (ei[2 * threadIdx.x + 1] != 0) atomicOr(&any, 1);
    __syncthreads();
    if (threadIdx.x == 0) mode[0] = (any == 0) ? 1 : 0;   // 1 => int64 layout
}

__device__ __forceinline__ void load_pair(const int* __restrict__ ei, int md, int u,
                                          int& a, int& b) {
    if (md) { a = ei[2 * u]; b = ei[2 * (E_UND + u)]; }
    else    { a = ei[u];     b = ei[E_UND + u]; }
}

// ---------------- degree count ----------------
__global__ void k_deg(const int* __restrict__ ei, const int* __restrict__ mode,
                      int* __restrict__ deg) {
    int i = blockIdx.x * 256 + threadIdx.x;
    if (i >= E_UND) return;
    int md = mode[0];
    int a, b;
    load_pair(ei, md, i, a, b);
    atomicAdd(&deg[a], 1);
    atomicAdd(&deg[b], 1);
}

// ---------------- exclusive scan (3 kernels) ----------------
__global__ __launch_bounds__(1024) void k_scan1(const int* __restrict__ deg,
                                                int* __restrict__ offs,
                                                int* __restrict__ bsum) {
    __shared__ int tmp[1024];
    int b = blockIdx.x, t = threadIdx.x;
    int i = b * 1024 + t;
    int v = (i < N_NODES) ? deg[i] : 0;
    tmp[t] = v;
    __syncthreads();
    for (int off = 1; off < 1024; off <<= 1) {
        int add = (t >= off) ? tmp[t - off] : 0;
        __syncthreads();
        tmp[t] += add;
        __syncthreads();
    }
    offs[i] = tmp[t] - v;              // exclusive within block
    if (t == 1023) bsum[b] = tmp[t];
}

__global__ void k_scan2(const int* __restrict__ bsum, int* __restrict__ bscan) {
    if (threadIdx.x == 0) {
        int run = 0;
        for (int b = 0; b < SCAN_NBLK; b++) { bscan[b] = run; run += bsum[b]; }
    }
}

__global__ void k_scan3(const int* __restrict__ deg, int* __restrict__ offs,
                        const int* __restrict__ bscan, int* __restrict__ cursor,
                        float* __restrict__ rsq) {
    int i = blockIdx.x * 256 + threadIdx.x;
    if (i >= N_NODES) return;
    int o = offs[i] + bscan[i >> 10];
    offs[i] = o;
    cursor[i] = o;
    int dg = deg[i];
    if (dg < 1) dg = 1;
    rsq[i] = rsqrtf((float)dg);
}

// ---------------- CSR fill (counting-sort scatter) ----------------
__global__ void k_fill(const int* __restrict__ ei, const int* __restrict__ mode,
                       int* __restrict__ cursor, const float* __restrict__ rsq,
                       int* __restrict__ edst, float* __restrict__ eval) {
    int i = blockIdx.x * 256 + threadIdx.x;
    if (i >= E_DIR) return;
    int md = mode[0];
    int u = (i < E_UND) ? i : i - E_UND;
    int a, b;
    load_pair(ei, md, u, a, b);
    int s, d;
    if (i < E_UND) { s = a; d = b; } else { s = b; d = a; }
    int slot = atomicAdd(&cursor[s], 1);
    edst[slot] = d;
    eval[slot] = rsq[s] * rsq[d];
}

// ---------------- user rows: transpose copy ----------------
__global__ void k_users(const float* __restrict__ ue, float* __restrict__ P,
                        float* __restrict__ S) {
    int idx = blockIdx.x * 256 + threadIdx.x;
    if (idx >= N_USERS * FF) return;
    int n = idx / FF;
    int r = idx - n * FF;
    int b = r >> 6, d = r & 63;
    float v = ue[((size_t)b * N_USERS + n) * DD + d];
    P[idx] = v;
    S[idx] = v;
}

// ---------------- item feature GEMM (fp32, 64x64 tile, all 3 sources) ------
template <int K>
__device__ __forceinline__ void gemm_part(const float* __restrict__ Xg,
                                          const float* __restrict__ Wg, int row0,
                                          int tid, int tx, int ty, float (&acc)[16],
                                          float (*Xs)[16], float (*Wsh)[64]) {
    for (int k0 = 0; k0 < K; k0 += 16) {
        {
            int r = tid >> 2;
            int kk = (tid & 3) << 2;
            int row = row0 + r;
            float4 v = make_float4(0.f, 0.f, 0.f, 0.f);
            if (row < N_ITEMS) v = *(const float4*)(Xg + (size_t)row * K + k0 + kk);
            *(float4*)(&Xs[r][kk]) = v;
        }
        {
            int kk = tid >> 4;
            int c = (tid & 15) << 2;
            *(float4*)(&Wsh[kk][c]) = *(const float4*)(Wg + (size_t)(k0 + kk) * 64 + c);
        }
        __syncthreads();
#pragma unroll
        for (int k4 = 0; k4 < 4; k4++) {
            float w0 = Wsh[k4 * 4 + 0][tx];
            float w1 = Wsh[k4 * 4 + 1][tx];
            float w2 = Wsh[k4 * 4 + 2][tx];
            float w3 = Wsh[k4 * 4 + 3][tx];
#pragma unroll
            for (int i = 0; i < 16; i++) {
                float4 xv = *(float4*)(&Xs[ty * 16 + i][k4 * 4]);
                acc[i] = fmaf(xv.x, w0, fmaf(xv.y, w1, fmaf(xv.z, w2, fmaf(xv.w, w3, acc[i]))));
            }
        }
        __syncthreads();
    }
}

__global__ __launch_bounds__(256) void k_item_gemm(
    const float* __restrict__ xt, const float* __restrict__ xi, const float* __restrict__ xs,
    const float* __restrict__ Wt, const float* __restrict__ Wi, const float* __restrict__ Wst,
    const float* __restrict__ bt, const float* __restrict__ bi, const float* __restrict__ bst,
    float* __restrict__ P, float* __restrict__ S) {
    const int b = blockIdx.y;
    const int row0 = blockIdx.x * 64;
    const int tid = threadIdx.x;
    const int tx = tid & 63;
    const int ty = tid >> 6;
    __shared__ float Xs[64][16];
    __shared__ float Wsh[16][64];
    float acc[16];
#pragma unroll
    for (int i = 0; i < 16; i++) acc[i] = 0.f;

    gemm_part<768>(xt, Wt + (size_t)b * 768 * 64, row0, tid, tx, ty, acc, Xs, Wsh);
    gemm_part<512>(xi, Wi + (size_t)b * 512 * 64, row0, tid, tx, ty, acc, Xs, Wsh);
    gemm_part<128>(xs, Wst + (size_t)b * 128 * 64, row0, tid, tx, ty, acc, Xs, Wsh);

    float bias = bt[b * 64 + tx] + bi[b * 64 + tx] + bst[b * 64 + tx];
#pragma unroll
    for (int i = 0; i < 16; i++) {
        int row = row0 + ty * 16 + i;
        if (row < N_ITEMS) {
            size_t idx = (size_t)(N_USERS + row) * FF + b * 64 + tx;
            float v = acc[i] + bias;
            P[idx] = v;
            S[idx] = v;
        }
    }
}

// ---------------- SPMM (pull; CSR by src), fused running-sum ----------------
__global__ __launch_bounds__(192) void k_spmm(const float* __restrict__ X,
                                              float* __restrict__ Y,
                                              float* __restrict__ S,
                                              const int* __restrict__ offs,
                                              const int* __restrict__ deg,
                                              const int* __restrict__ edst,
                                              const float* __restrict__ eval) {
    int n = blockIdx.x;
    int t = threadIdx.x;
    int start = offs[n];
    int dg = deg[n];
    float acc = 0.f;
    for (int j = 0; j < dg; j++) {
        int d = edst[start + j];
        float v = eval[start + j];
        acc = fmaf(v, X[(size_t)d * FF + t], acc);
    }
    size_t o = (size_t)n * FF + t;
    Y[o] = acc;
    S[o] += acc;
}

// ---------------- attention MLP + readout (8 nodes/block) ----------------
__global__ __launch_bounds__(128) void k_attn(
    const float* __restrict__ S,
    const float* __restrict__ Wu1, const float* __restrict__ bu1,
    const float* __restrict__ Wu2, const float* __restrict__ bu2,
    const float* __restrict__ Wi1, const float* __restrict__ bi1,
    const float* __restrict__ Wi2, const float* __restrict__ bi2,
    float* __restrict__ out) {
    const int NPB = 8;
    int blk = blockIdx.x;
    int node0;
    const float *W1, *B1, *W2, *B2;
    if (blk < N_USERS / NPB) {
        node0 = blk * NPB;
        W1 = Wu1; B1 = bu1; W2 = Wu2; B2 = bu2;
    } else {
        node0 = N_USERS + (blk - N_USERS / NPB) * NPB;
        W1 = Wi1; B1 = bi1; W2 = Wi2; B2 = bi2;
    }
    int t = threadIdx.x;
    __shared__ float hl[NPB][FF];
    __shared__ float hid[NPB][128];
    __shared__ float lg[NPB][3];
    __shared__ float aw[NPB][3];

    const float inv3 = 1.f / 3.f;
#pragma unroll
    for (int q = 0; q < 12; q++) {
        int flat = q * 128 + t;            // 0..1535 = 8*192
        int m = flat / FF;
        int r = flat - m * FF;
        hl[m][r] = S[(size_t)(node0 + m) * FF + r] * inv3;
    }
    __syncthreads();

    {
        float accm[NPB];
        float bb = B1[t];
#pragma unroll
        for (int m = 0; m < NPB; m++) accm[m] = bb;
        for (int k = 0; k < FF; k += 4) {
            float w0 = W1[(k + 0) * 128 + t];
            float w1 = W1[(k + 1) * 128 + t];
            float w2 = W1[(k + 2) * 128 + t];
            float w3 = W1[(k + 3) * 128 + t];
#pragma unroll
            for (int m = 0; m < NPB; m++) {
                float4 x = *(float4*)(&hl[m][k]);
                accm[m] = fmaf(x.x, w0, fmaf(x.y, w1, fmaf(x.z, w2, fmaf(x.w, w3, accm[m]))));
            }
        }
#pragma unroll
        for (int m = 0; m < NPB; m++) hid[m][t] = fmaxf(accm[m], 0.f);
    }
    __syncthreads();

    if (t < NPB * 3) {
        int m = t / 3, c = t - m * 3;
        float s = B2[c];
        for (int j = 0; j < 128; j++) s = fmaf(hid[m][j], W2[j * 3 + c], s);
        lg[m][c] = s;
    }
    __syncthreads();

    if (t < NPB) {
        float l0 = lg[t][0], l1 = lg[t][1], l2 = lg[t][2];
        float mx = fmaxf(l0, fmaxf(l1, l2));
        float e0 = expf(l0 - mx), e1 = expf(l1 - mx), e2 = expf(l2 - mx);
        float inv = 1.f / (e0 + e1 + e2);
        aw[t][0] = e0 * inv; aw[t][1] = e1 * inv; aw[t][2] = e2 * inv;
    }
    __syncthreads();

#pragma unroll
    for (int q = 0; q < 4; q++) {
        int flat = q * 128 + t;            // 0..511 = 8*64
        int m = flat >> 6, d = flat & 63;
        out[(size_t)(node0 + m) * DD + d] =
            aw[m][0] * hl[m][d] + aw[m][1] * hl[m][64 + d] + aw[m][2] * hl[m][128 + d];
    }
}

// ---------------- launch ----------------
extern "C" void kernel_launch(void* const* d_in, const int* in_sizes, int n_in,
                              void* d_out, int out_size, void* d_ws, size_t ws_size,
                              hipStream_t stream) {
    (void)in_sizes; (void)n_in; (void)out_size; (void)ws_size;
    const float* x_txt    = (const float*)d_in[0];
    const float* x_img    = (const float*)d_in[1];
    const float* x_struct = (const float*)d_in[2];
    const float* user_emb = (const float*)d_in[3];
    const float* W_txt    = (const float*)d_in[4];
    const float* b_txt    = (const float*)d_in[5];
    const float* W_img    = (const float*)d_in[6];
    const float* b_img    = (const float*)d_in[7];
    const float* W_st     = (const float*)d_in[8];
    const float* b_st     = (const float*)d_in[9];
    const float* Wu1      = (const float*)d_in[10];
    const float* bu1      = (const float*)d_in[11];
    const float* Wu2      = (const float*)d_in[12];
    const float* bu2      = (const float*)d_in[13];
    const float* Wi1      = (const float*)d_in[14];
    const float* bi1      = (const float*)d_in[15];
    const float* Wi2      = (const float*)d_in[16];
    const float* bi2      = (const float*)d_in[17];
    const int*   ei       = (const int*)d_in[18];
    float* out = (float*)d_out;

    char* base = (char*)d_ws;
    size_t off = 0;
    auto take = [&](size_t bytes) -> void* {
        void* p = base + off;
        off += (bytes + 255) & ~(size_t)255;
        return p;
    };
    float* P    = (float*)take((size_t)N_NODES * FF * 4);
    float* Q    = (float*)take((size_t)N_NODES * FF * 4);
    float* S    = (float*)take((size_t)N_NODES * FF * 4);
    int* deg    = (int*)take((size_t)N_NODES * 4);
    int* offs   = (int*)take((size_t)SCAN_NBLK * 1024 * 4);
    int* cursor = (int*)take((size_t)N_NODES * 4);
    int* bsum   = (int*)take((size_t)SCAN_NBLK * 4);
    int* bscan  = (int*)take((size_t)SCAN_NBLK * 4);
    float* rsq  = (float*)take((size_t)N_NODES * 4);
    int* edst   = (int*)take((size_t)E_DIR * 4);
    float* eval = (float*)take((size_t)E_DIR * 4);
    int* mode   = (int*)take(256);

    hipMemsetAsync(deg, 0, (size_t)N_NODES * 4, stream);

    k_mode<<<1, 256, 0, stream>>>(ei, mode);
    k_deg<<<(E_UND + 255) / 256, 256, 0, stream>>>(ei, mode, deg);
    k_scan1<<<SCAN_NBLK, 1024, 0, stream>>>(deg, offs, bsum);
    k_scan2<<<1, 64, 0, stream>>>(bsum, bscan);
    k_scan3<<<(N_NODES + 255) / 256, 256, 0, stream>>>(deg, offs, bscan, cursor, rsq);
    k_fill<<<(E_DIR + 255) / 256, 256, 0, stream>>>(ei, mode, cursor, rsq, edst, eval);

    k_users<<<(N_USERS * FF + 255) / 256, 256, 0, stream>>>(user_emb, P, S);
    k_item_gemm<<<dim3((N_ITEMS + 63) / 64, 3), 256, 0, stream>>>(
        x_txt, x_img, x_struct, W_txt, W_img, W_st, b_txt, b_img, b_st, P, S);

    k_spmm<<<N_NODES, 192, 0, stream>>>(P, Q, S, offs, deg, edst, eval);
    k_spmm<<<N_NODES, 192, 0, stream>>>(Q, P, S, offs, deg, edst, eval);

    k_attn<<<N_NODES / 8, 128, 0, stream>>>(S, Wu1, bu1, Wu2, bu2, Wi1, bi1, Wi2, bi2, out);
}

// Round 2
// 997.118 us; speedup vs baseline: 1.3732x; 1.3732x over previous
//
#include <hip/hip_runtime.h>
#include <math.h>

#define N_USERS 60000
#define N_ITEMS 30000
#define N_NODES 90000
#define DD 64
#define FF 192              // 3*DD
#define KK_TOT 1408         // 768 + 512 + 128
#define E_UND 500000
#define E_DIR 1000000
#define SCAN_NBLK 88        // ceil(90000/1024)

typedef __attribute__((ext_vector_type(8))) __bf16 bf16x8;
typedef __attribute__((ext_vector_type(8))) unsigned short u16x8;
typedef __attribute__((ext_vector_type(4))) float f32x4;

__device__ __forceinline__ unsigned short f2bf(float f) {
    unsigned int u = __float_as_uint(f);
    unsigned int r = (u + 0x7FFFu + ((u >> 16) & 1u)) >> 16;   // RNE
    return (unsigned short)r;
}

// ---------------- edge-layout probe: int32 vs int64 storage ----------------
__global__ void k_mode(const int* __restrict__ ei, int* __restrict__ mode) {
    __shared__ int any;
    if (threadIdx.x == 0) any = 0;
    __syncthreads();
    if (ei[2 * threadIdx.x + 1] != 0) atomicOr(&any, 1);
    __syncthreads();
    if (threadIdx.x == 0) mode[0] = (any == 0) ? 1 : 0;   // 1 => int64 layout
}

__device__ __forceinline__ void load_pair(const int* __restrict__ ei, int md, int u,
                                          int& a, int& b) {
    if (md) { a = ei[2 * u]; b = ei[2 * (E_UND + u)]; }
    else    { a = ei[u];     b = ei[E_UND + u]; }
}

// ---------------- degree count ----------------
__global__ void k_deg(const int* __restrict__ ei, const int* __restrict__ mode,
                      int* __restrict__ deg) {
    int i = blockIdx.x * 256 + threadIdx.x;
    if (i >= E_UND) return;
    int md = mode[0];
    int a, b;
    load_pair(ei, md, i, a, b);
    atomicAdd(&deg[a], 1);
    atomicAdd(&deg[b], 1);
}

// ---------------- exclusive scan (3 kernels) ----------------
__global__ __launch_bounds__(1024) void k_scan1(const int* __restrict__ deg,
                                                int* __restrict__ offs,
                                                int* __restrict__ bsum) {
    __shared__ int tmp[1024];
    int b = blockIdx.x, t = threadIdx.x;
    int i = b * 1024 + t;
    int v = (i < N_NODES) ? deg[i] : 0;
    tmp[t] = v;
    __syncthreads();
    for (int off = 1; off < 1024; off <<= 1) {
        int add = (t >= off) ? tmp[t - off] : 0;
        __syncthreads();
        tmp[t] += add;
        __syncthreads();
    }
    offs[i] = tmp[t] - v;              // exclusive within block
    if (t == 1023) bsum[b] = tmp[t];
}

__global__ void k_scan2(const int* __restrict__ bsum, int* __restrict__ bscan) {
    if (threadIdx.x == 0) {
        int run = 0;
        for (int b = 0; b < SCAN_NBLK; b++) { bscan[b] = run; run += bsum[b]; }
    }
}

__global__ void k_scan3(const int* __restrict__ deg, int* __restrict__ offs,
                        const int* __restrict__ bscan, int* __restrict__ cursor,
                        float* __restrict__ rsq) {
    int i = blockIdx.x * 256 + threadIdx.x;
    if (i >= N_NODES) return;
    int o = offs[i] + bscan[i >> 10];
    offs[i] = o;
    cursor[i] = o;
    int dg = deg[i];
    if (dg < 1) dg = 1;
    rsq[i] = rsqrtf((float)dg);
}

// ---------------- CSR fill (counting-sort scatter) ----------------
__global__ void k_fill(const int* __restrict__ ei, const int* __restrict__ mode,
                       int* __restrict__ cursor, const float* __restrict__ rsq,
                       int* __restrict__ edst, float* __restrict__ eval) {
    int i = blockIdx.x * 256 + threadIdx.x;
    if (i >= E_DIR) return;
    int md = mode[0];
    int u = (i < E_UND) ? i : i - E_UND;
    int a, b;
    load_pair(ei, md, u, a, b);
    int s, d;
    if (i < E_UND) { s = a; d = b; } else { s = b; d = a; }
    int slot = atomicAdd(&cursor[s], 1);
    edst[slot] = d;
    eval[slot] = rsq[s] * rsq[d];
}

// ---------------- user rows: transpose copy ----------------
__global__ void k_users(const float* __restrict__ ue, float* __restrict__ P,
                        float* __restrict__ S) {
    int idx = blockIdx.x * 256 + threadIdx.x;
    if (idx >= N_USERS * FF) return;
    int n = idx / FF;
    int r = idx - n * FF;
    int b = r >> 6, d = r & 63;
    float v = ue[((size_t)b * N_USERS + n) * DD + d];
    P[idx] = v;
    S[idx] = v;
}

// ---------------- W transpose+concat+bf16: Wtb[n][k], n=b*64+d ----------------
__global__ void k_cvt_w(const float* __restrict__ Wt, const float* __restrict__ Wi,
                        const float* __restrict__ Wst, unsigned short* __restrict__ Wtb) {
    int idx = blockIdx.x * 256 + threadIdx.x;
    if (idx >= FF * KK_TOT) return;
    int n = idx / KK_TOT;
    int k = idx - n * KK_TOT;
    int b = n >> 6, d = n & 63;
    float v;
    if (k < 768)       v = Wt [((size_t)b * 768 + k) * 64 + d];
    else if (k < 1280) v = Wi [((size_t)b * 512 + (k - 768)) * 64 + d];
    else               v = Wst[((size_t)b * 128 + (k - 1280)) * 64 + d];
    Wtb[idx] = f2bf(v);
}

// ---------------- item feature GEMM: bf16 MFMA, M=30000 N=192 K=1408 -------
// Tile 128x64, BK=64, 4 waves: wave w owns rows [w*32, w*32+32), all 64 cols.
#define BM 128
#define BN 64
#define BK 64
#define LDK 72   // padded LDS pitch (elements); 72*2B=144B breaks 128B-stride conflicts

__global__ __launch_bounds__(256) void k_item_gemm_mfma(
    const float* __restrict__ xt, const float* __restrict__ xi, const float* __restrict__ xs,
    const unsigned short* __restrict__ Wtb,
    const float* __restrict__ bt, const float* __restrict__ bi, const float* __restrict__ bst,
    float* __restrict__ P, float* __restrict__ S) {
    __shared__ unsigned short Ash[BM * LDK];
    __shared__ unsigned short Bsh[BN * LDK];
    const int tid  = threadIdx.x;
    const int wave = tid >> 6;
    const int lane = tid & 63;
    const int row0 = blockIdx.x * BM;
    const int n0   = blockIdx.y * BN;     // head b = blockIdx.y

    f32x4 acc[2][4];
#pragma unroll
    for (int tm = 0; tm < 2; tm++)
#pragma unroll
        for (int tn = 0; tn < 4; tn++) acc[tm][tn] = (f32x4){0.f, 0.f, 0.f, 0.f};

    for (int k0 = 0; k0 < KK_TOT; k0 += BK) {
        // --- stage A: 128 rows x 64 k, fp32 -> bf16 on the fly -------------
        // chunk = 8 elements; 128*8 = 1024 chunks; 4 per thread
#pragma unroll
        for (int i = 0; i < 4; i++) {
            int id = tid + i * 256;
            int r = id >> 3;
            int c = (id & 7) << 3;
            int gr = row0 + r;
            int gk = k0 + c;              // k0 multiple of 64 -> slice never crosses 768/1280
            float4 v0 = make_float4(0.f, 0.f, 0.f, 0.f);
            float4 v1 = v0;
            if (gr < N_ITEMS) {
                const float* src;
                int kl;
                if (gk < 768)       { src = xt + (size_t)gr * 768; kl = gk; }
                else if (gk < 1280) { src = xi + (size_t)gr * 512; kl = gk - 768; }
                else                { src = xs + (size_t)gr * 128; kl = gk - 1280; }
                v0 = *(const float4*)(src + kl);
                v1 = *(const float4*)(src + kl + 4);
            }
            u16x8 pk;
            pk[0] = f2bf(v0.x); pk[1] = f2bf(v0.y); pk[2] = f2bf(v0.z); pk[3] = f2bf(v0.w);
            pk[4] = f2bf(v1.x); pk[5] = f2bf(v1.y); pk[6] = f2bf(v1.z); pk[7] = f2bf(v1.w);
            *(u16x8*)(&Ash[r * LDK + c]) = pk;
        }
        // --- stage B: 64 n-rows x 64 k, bf16 16B copy ----------------------
#pragma unroll
        for (int i = 0; i < 2; i++) {
            int id = tid + i * 256;
            int r = id >> 3;
            int c = (id & 7) << 3;
            *(u16x8*)(&Bsh[r * LDK + c]) =
                *(const u16x8*)(&Wtb[(size_t)(n0 + r) * KK_TOT + k0 + c]);
        }
        __syncthreads();
        // --- MFMA ----------------------------------------------------------
#pragma unroll
        for (int kk = 0; kk < BK; kk += 32) {
            bf16x8 af[2], bfr[4];
#pragma unroll
            for (int tm = 0; tm < 2; tm++)
                af[tm] = *(const bf16x8*)(&Ash[(wave * 32 + tm * 16 + (lane & 15)) * LDK +
                                               kk + (lane >> 4) * 8]);
#pragma unroll
            for (int tn = 0; tn < 4; tn++)
                bfr[tn] = *(const bf16x8*)(&Bsh[(tn * 16 + (lane & 15)) * LDK +
                                                kk + (lane >> 4) * 8]);
#pragma unroll
            for (int tm = 0; tm < 2; tm++)
#pragma unroll
                for (int tn = 0; tn < 4; tn++)
                    acc[tm][tn] = __builtin_amdgcn_mfma_f32_16x16x32_bf16(
                        af[tm], bfr[tn], acc[tm][tn], 0, 0, 0);
        }
        __syncthreads();
    }

    // --- epilogue: C/D layout col=lane&15, row=quad*4+reg ------------------
    const int col16 = lane & 15;
    const int quad  = lane >> 4;
    const int b = blockIdx.y;
#pragma unroll
    for (int tn = 0; tn < 4; tn++) {
        int d = tn * 16 + col16;
        int n = n0 + d;
        float bias = bt[b * 64 + d] + bi[b * 64 + d] + bst[b * 64 + d];
#pragma unroll
        for (int tm = 0; tm < 2; tm++) {
#pragma unroll
            for (int r = 0; r < 4; r++) {
                int row = row0 + wave * 32 + tm * 16 + quad * 4 + r;
                if (row < N_ITEMS) {
                    size_t idx = (size_t)(N_USERS + row) * FF + n;
                    float v = acc[tm][tn][r] + bias;
                    P[idx] = v;
                    S[idx] = v;
                }
            }
        }
    }
}

// ---------------- SPMM (pull; CSR by src), fused running-sum ----------------
__global__ __launch_bounds__(192) void k_spmm(const float* __restrict__ X,
                                              float* __restrict__ Y,
                                              float* __restrict__ S,
                                              const int* __restrict__ offs,
                                              const int* __restrict__ deg,
                                              const int* __restrict__ edst,
                                              const float* __restrict__ eval) {
    int n = blockIdx.x;
    int t = threadIdx.x;
    int start = offs[n];
    int dg = deg[n];
    float acc = 0.f;
    for (int j = 0; j < dg; j++) {
        int d = edst[start + j];
        float v = eval[start + j];
        acc = fmaf(v, X[(size_t)d * FF + t], acc);
    }
    size_t o = (size_t)n * FF + t;
    Y[o] = acc;
    S[o] += acc;
}

// ---------------- attention MLP + readout (8 nodes/block) ----------------
__global__ __launch_bounds__(128) void k_attn(
    const float* __restrict__ S,
    const float* __restrict__ Wu1, const float* __restrict__ bu1,
    const float* __restrict__ Wu2, const float* __restrict__ bu2,
    const float* __restrict__ Wi1, const float* __restrict__ bi1,
    const float* __restrict__ Wi2, const float* __restrict__ bi2,
    float* __restrict__ out) {
    const int NPB = 8;
    int blk = blockIdx.x;
    int node0;
    const float *W1, *B1, *W2, *B2;
    if (blk < N_USERS / NPB) {
        node0 = blk * NPB;
        W1 = Wu1; B1 = bu1; W2 = Wu2; B2 = bu2;
    } else {
        node0 = N_USERS + (blk - N_USERS / NPB) * NPB;
        W1 = Wi1; B1 = bi1; W2 = Wi2; B2 = bi2;
    }
    int t = threadIdx.x;
    __shared__ float hl[NPB][FF];
    __shared__ float hid[NPB][128];
    __shared__ float lg[NPB][3];
    __shared__ float aw[NPB][3];

    const float inv3 = 1.f / 3.f;
#pragma unroll
    for (int q = 0; q < 12; q++) {
        int flat = q * 128 + t;            // 0..1535 = 8*192
        int m = flat / FF;
        int r = flat - m * FF;
        hl[m][r] = S[(size_t)(node0 + m) * FF + r] * inv3;
    }
    __syncthreads();

    {
        float accm[NPB];
        float bb = B1[t];
#pragma unroll
        for (int m = 0; m < NPB; m++) accm[m] = bb;
        for (int k = 0; k < FF; k += 4) {
            float w0 = W1[(k + 0) * 128 + t];
            float w1 = W1[(k + 1) * 128 + t];
            float w2 = W1[(k + 2) * 128 + t];
            float w3 = W1[(k + 3) * 128 + t];
#pragma unroll
            for (int m = 0; m < NPB; m++) {
                float4 x = *(float4*)(&hl[m][k]);
                accm[m] = fmaf(x.x, w0, fmaf(x.y, w1, fmaf(x.z, w2, fmaf(x.w, w3, accm[m]))));
            }
        }
#pragma unroll
        for (int m = 0; m < NPB; m++) hid[m][t] = fmaxf(accm[m], 0.f);
    }
    __syncthreads();

    if (t < NPB * 3) {
        int m = t / 3, c = t - m * 3;
        float s = B2[c];
        for (int j = 0; j < 128; j++) s = fmaf(hid[m][j], W2[j * 3 + c], s);
        lg[m][c] = s;
    }
    __syncthreads();

    if (t < NPB) {
        float l0 = lg[t][0], l1 = lg[t][1], l2 = lg[t][2];
        float mx = fmaxf(l0, fmaxf(l1, l2));
        float e0 = expf(l0 - mx), e1 = expf(l1 - mx), e2 = expf(l2 - mx);
        float inv = 1.f / (e0 + e1 + e2);
        aw[t][0] = e0 * inv; aw[t][1] = e1 * inv; aw[t][2] = e2 * inv;
    }
    __syncthreads();

#pragma unroll
    for (int q = 0; q < 4; q++) {
        int flat = q * 128 + t;            // 0..511 = 8*64
        int m = flat >> 6, d = flat & 63;
        out[(size_t)(node0 + m) * DD + d] =
            aw[m][0] * hl[m][d] + aw[m][1] * hl[m][64 + d] + aw[m][2] * hl[m][128 + d];
    }
}

// ---------------- launch ----------------
extern "C" void kernel_launch(void* const* d_in, const int* in_sizes, int n_in,
                              void* d_out, int out_size, void* d_ws, size_t ws_size,
                              hipStream_t stream) {
    (void)in_sizes; (void)n_in; (void)out_size; (void)ws_size;
    const float* x_txt    = (const float*)d_in[0];
    const float* x_img    = (const float*)d_in[1];
    const float* x_struct = (const float*)d_in[2];
    const float* user_emb = (const float*)d_in[3];
    const float* W_txt    = (const float*)d_in[4];
    const float* b_txt    = (const float*)d_in[5];
    const float* W_img    = (const float*)d_in[6];
    const float* b_img    = (const float*)d_in[7];
    const float* W_st     = (const float*)d_in[8];
    const float* b_st     = (const float*)d_in[9];
    const float* Wu1      = (const float*)d_in[10];
    const float* bu1      = (const float*)d_in[11];
    const float* Wu2      = (const float*)d_in[12];
    const float* bu2      = (const float*)d_in[13];
    const float* Wi1      = (const float*)d_in[14];
    const float* bi1      = (const float*)d_in[15];
    const float* Wi2      = (const float*)d_in[16];
    const float* bi2      = (const float*)d_in[17];
    const int*   ei       = (const int*)d_in[18];
    float* out = (float*)d_out;

    char* base = (char*)d_ws;
    size_t off = 0;
    auto take = [&](size_t bytes) -> void* {
        void* p = base + off;
        off += (bytes + 255) & ~(size_t)255;
        return p;
    };
    float* P    = (float*)take((size_t)N_NODES * FF * 4);
    float* Q    = (float*)take((size_t)N_NODES * FF * 4);
    float* S    = (float*)take((size_t)N_NODES * FF * 4);
    int* deg    = (int*)take((size_t)N_NODES * 4);
    int* offs   = (int*)take((size_t)SCAN_NBLK * 1024 * 4);
    int* cursor = (int*)take((size_t)N_NODES * 4);
    int* bsum   = (int*)take((size_t)SCAN_NBLK * 4);
    int* bscan  = (int*)take((size_t)SCAN_NBLK * 4);
    float* rsq  = (float*)take((size_t)N_NODES * 4);
    int* edst   = (int*)take((size_t)E_DIR * 4);
    float* eval = (float*)take((size_t)E_DIR * 4);
    int* mode   = (int*)take(256);
    unsigned short* Wtb = (unsigned short*)take((size_t)FF * KK_TOT * 2);

    hipMemsetAsync(deg, 0, (size_t)N_NODES * 4, stream);

    k_mode<<<1, 256, 0, stream>>>(ei, mode);
    k_deg<<<(E_UND + 255) / 256, 256, 0, stream>>>(ei, mode, deg);
    k_scan1<<<SCAN_NBLK, 1024, 0, stream>>>(deg, offs, bsum);
    k_scan2<<<1, 64, 0, stream>>>(bsum, bscan);
    k_scan3<<<(N_NODES + 255) / 256, 256, 0, stream>>>(deg, offs, bscan, cursor, rsq);
    k_fill<<<(E_DIR + 255) / 256, 256, 0, stream>>>(ei, mode, cursor, rsq, edst, eval);

    k_users<<<(N_USERS * FF + 255) / 256, 256, 0, stream>>>(user_emb, P, S);
    k_cvt_w<<<(FF * KK_TOT + 255) / 256, 256, 0, stream>>>(W_txt, W_img, W_st, Wtb);
    k_item_gemm_mfma<<<dim3((N_ITEMS + BM - 1) / BM, 3), 256, 0, stream>>>(
        x_txt, x_img, x_struct, Wtb, b_txt, b_img, b_st, P, S);

    k_spmm<<<N_NODES, 192, 0, stream>>>(P, Q, S, offs, deg, edst, eval);
    k_spmm<<<N_NODES, 192, 0, stream>>>(Q, P, S, offs, deg, edst, eval);

    k_attn<<<N_NODES / 8, 128, 0, stream>>>(S, Wu1, bu1, Wu2, bu2, Wi1, bi1, Wi2, bi2, out);
}

// Round 3
// 788.218 us; speedup vs baseline: 1.7372x; 1.2650x over previous
//
#include <hip/hip_runtime.h>
#include <math.h>

#define N_USERS 60000
#define N_ITEMS 30000
#define N_NODES 90000
#define DD 64
#define FF 192              // 3*DD
#define FH 96               // FF/2 (bf16 pairs per row)
#define KK_TOT 1408         // 768 + 512 + 128
#define E_UND 500000
#define E_DIR 1000000
#define SCAN_NBLK 88        // ceil(90000/1024)

typedef __attribute__((ext_vector_type(8))) __bf16 bf16x8;
typedef __attribute__((ext_vector_type(8))) unsigned short u16x8;
typedef __attribute__((ext_vector_type(4))) float f32x4;

__device__ __forceinline__ unsigned short f2bf(float f) {
    unsigned int u = __float_as_uint(f);
    unsigned int r = (u + 0x7FFFu + ((u >> 16) & 1u)) >> 16;   // RNE
    return (unsigned short)r;
}
__device__ __forceinline__ float bf_lo(unsigned int x) { return __uint_as_float(x << 16); }
__device__ __forceinline__ float bf_hi(unsigned int x) { return __uint_as_float(x & 0xFFFF0000u); }
__device__ __forceinline__ unsigned int pack2(float a, float b) {
    return ((unsigned int)f2bf(b) << 16) | (unsigned int)f2bf(a);
}

// ---------------- edge-layout probe: int32 vs int64 storage ----------------
__global__ void k_mode(const int* __restrict__ ei, int* __restrict__ mode) {
    __shared__ int any;
    if (threadIdx.x == 0) any = 0;
    __syncthreads();
    if (ei[2 * threadIdx.x + 1] != 0) atomicOr(&any, 1);
    __syncthreads();
    if (threadIdx.x == 0) mode[0] = (any == 0) ? 1 : 0;   // 1 => int64 layout
}

__device__ __forceinline__ void load_pair(const int* __restrict__ ei, int md, int u,
                                          int& a, int& b) {
    if (md) { a = ei[2 * u]; b = ei[2 * (E_UND + u)]; }
    else    { a = ei[u];     b = ei[E_UND + u]; }
}

// ---------------- degree count ----------------
__global__ void k_deg(const int* __restrict__ ei, const int* __restrict__ mode,
                      int* __restrict__ deg) {
    int i = blockIdx.x * 256 + threadIdx.x;
    if (i >= E_UND) return;
    int md = mode[0];
    int a, b;
    load_pair(ei, md, i, a, b);
    atomicAdd(&deg[a], 1);
    atomicAdd(&deg[b], 1);
}

// ---------------- exclusive scan (3 kernels) ----------------
__global__ __launch_bounds__(1024) void k_scan1(const int* __restrict__ deg,
                                                int* __restrict__ offs,
                                                int* __restrict__ bsum) {
    __shared__ int tmp[1024];
    int b = blockIdx.x, t = threadIdx.x;
    int i = b * 1024 + t;
    int v = (i < N_NODES) ? deg[i] : 0;
    tmp[t] = v;
    __syncthreads();
    for (int off = 1; off < 1024; off <<= 1) {
        int add = (t >= off) ? tmp[t - off] : 0;
        __syncthreads();
        tmp[t] += add;
        __syncthreads();
    }
    offs[i] = tmp[t] - v;              // exclusive within block
    if (t == 1023) bsum[b] = tmp[t];
}

__global__ void k_scan2(const int* __restrict__ bsum, int* __restrict__ bscan) {
    if (threadIdx.x == 0) {
        int run = 0;
        for (int b = 0; b < SCAN_NBLK; b++) { bscan[b] = run; run += bsum[b]; }
    }
}

__global__ void k_scan3(const int* __restrict__ deg, int* __restrict__ offs,
                        const int* __restrict__ bscan, int* __restrict__ cursor,
                        float* __restrict__ rsq) {
    int i = blockIdx.x * 256 + threadIdx.x;
    if (i >= N_NODES) return;
    int o = offs[i] + bscan[i >> 10];
    offs[i] = o;
    cursor[i] = o;
    int dg = deg[i];
    if (dg < 1) dg = 1;
    rsq[i] = rsqrtf((float)dg);
}

// ---------------- CSR fill (counting-sort scatter) ----------------
__global__ void k_fill(const int* __restrict__ ei, const int* __restrict__ mode,
                       int* __restrict__ cursor, const float* __restrict__ rsq,
                       int* __restrict__ edst, float* __restrict__ eval) {
    int i = blockIdx.x * 256 + threadIdx.x;
    if (i >= E_DIR) return;
    int md = mode[0];
    int u = (i < E_UND) ? i : i - E_UND;
    int a, b;
    load_pair(ei, md, u, a, b);
    int s, d;
    if (i < E_UND) { s = a; d = b; } else { s = b; d = a; }
    int slot = atomicAdd(&cursor[s], 1);
    edst[slot] = d;
    eval[slot] = rsq[s] * rsq[d];
}

// ---------------- user rows: transpose copy into S ----------------
__global__ void k_users(const float* __restrict__ ue, float* __restrict__ S) {
    int idx = blockIdx.x * 256 + threadIdx.x;
    if (idx >= N_USERS * FF) return;
    int n = idx / FF;
    int r = idx - n * FF;
    int b = r >> 6, d = r & 63;
    S[idx] = ue[((size_t)b * N_USERS + n) * DD + d];
}

// ---------------- W transpose+concat+bf16: Wtb[n][k], n=b*64+d ----------------
__global__ void k_cvt_w(const float* __restrict__ Wt, const float* __restrict__ Wi,
                        const float* __restrict__ Wst, unsigned short* __restrict__ Wtb) {
    int idx = blockIdx.x * 256 + threadIdx.x;
    if (idx >= FF * KK_TOT) return;
    int n = idx / KK_TOT;
    int k = idx - n * KK_TOT;
    int b = n >> 6, d = n & 63;
    float v;
    if (k < 768)       v = Wt [((size_t)b * 768 + k) * 64 + d];
    else if (k < 1280) v = Wi [((size_t)b * 512 + (k - 768)) * 64 + d];
    else               v = Wst[((size_t)b * 128 + (k - 1280)) * 64 + d];
    Wtb[idx] = f2bf(v);
}

// ---------------- item feature GEMM: bf16 MFMA, M=30000 N=192 K=1408 -------
#define BM 128
#define BN 64
#define BK 64
#define LDK 72   // padded LDS pitch (elements)

__global__ __launch_bounds__(256) void k_item_gemm_mfma(
    const float* __restrict__ xt, const float* __restrict__ xi, const float* __restrict__ xs,
    const unsigned short* __restrict__ Wtb,
    const float* __restrict__ bt, const float* __restrict__ bi, const float* __restrict__ bst,
    float* __restrict__ S) {
    __shared__ unsigned short Ash[BM * LDK];
    __shared__ unsigned short Bsh[BN * LDK];
    const int tid  = threadIdx.x;
    const int wave = tid >> 6;
    const int lane = tid & 63;
    const int row0 = blockIdx.x * BM;
    const int n0   = blockIdx.y * BN;     // head b = blockIdx.y

    f32x4 acc[2][4];
#pragma unroll
    for (int tm = 0; tm < 2; tm++)
#pragma unroll
        for (int tn = 0; tn < 4; tn++) acc[tm][tn] = (f32x4){0.f, 0.f, 0.f, 0.f};

    for (int k0 = 0; k0 < KK_TOT; k0 += BK) {
#pragma unroll
        for (int i = 0; i < 4; i++) {
            int id = tid + i * 256;
            int r = id >> 3;
            int c = (id & 7) << 3;
            int gr = row0 + r;
            int gk = k0 + c;
            float4 v0 = make_float4(0.f, 0.f, 0.f, 0.f);
            float4 v1 = v0;
            if (gr < N_ITEMS) {
                const float* src;
                int kl;
                if (gk < 768)       { src = xt + (size_t)gr * 768; kl = gk; }
                else if (gk < 1280) { src = xi + (size_t)gr * 512; kl = gk - 768; }
                else                { src = xs + (size_t)gr * 128; kl = gk - 1280; }
                v0 = *(const float4*)(src + kl);
                v1 = *(const float4*)(src + kl + 4);
            }
            u16x8 pk;
            pk[0] = f2bf(v0.x); pk[1] = f2bf(v0.y); pk[2] = f2bf(v0.z); pk[3] = f2bf(v0.w);
            pk[4] = f2bf(v1.x); pk[5] = f2bf(v1.y); pk[6] = f2bf(v1.z); pk[7] = f2bf(v1.w);
            *(u16x8*)(&Ash[r * LDK + c]) = pk;
        }
#pragma unroll
        for (int i = 0; i < 2; i++) {
            int id = tid + i * 256;
            int r = id >> 3;
            int c = (id & 7) << 3;
            *(u16x8*)(&Bsh[r * LDK + c]) =
                *(const u16x8*)(&Wtb[(size_t)(n0 + r) * KK_TOT + k0 + c]);
        }
        __syncthreads();
#pragma unroll
        for (int kk = 0; kk < BK; kk += 32) {
            bf16x8 af[2], bfr[4];
#pragma unroll
            for (int tm = 0; tm < 2; tm++)
                af[tm] = *(const bf16x8*)(&Ash[(wave * 32 + tm * 16 + (lane & 15)) * LDK +
                                               kk + (lane >> 4) * 8]);
#pragma unroll
            for (int tn = 0; tn < 4; tn++)
                bfr[tn] = *(const bf16x8*)(&Bsh[(tn * 16 + (lane & 15)) * LDK +
                                                kk + (lane >> 4) * 8]);
#pragma unroll
            for (int tm = 0; tm < 2; tm++)
#pragma unroll
                for (int tn = 0; tn < 4; tn++)
                    acc[tm][tn] = __builtin_amdgcn_mfma_f32_16x16x32_bf16(
                        af[tm], bfr[tn], acc[tm][tn], 0, 0, 0);
        }
        __syncthreads();
    }

    const int col16 = lane & 15;
    const int quad  = lane >> 4;
    const int b = blockIdx.y;
#pragma unroll
    for (int tn = 0; tn < 4; tn++) {
        int d = tn * 16 + col16;
        int n = n0 + d;
        float bias = bt[b * 64 + d] + bi[b * 64 + d] + bst[b * 64 + d];
#pragma unroll
        for (int tm = 0; tm < 2; tm++) {
#pragma unroll
            for (int r = 0; r < 4; r++) {
                int row = row0 + wave * 32 + tm * 16 + quad * 4 + r;
                if (row < N_ITEMS) {
                    S[(size_t)(N_USERS + row) * FF + n] = acc[tm][tn][r] + bias;
                }
            }
        }
    }
}

// ---------------- pack fp32 S -> bf16-pair rows ----------------
__global__ void k_pack(const float* __restrict__ S, unsigned int* __restrict__ Xb) {
    int i = blockIdx.x * 256 + threadIdx.x;
    if (i >= N_NODES * FH) return;
    float2 v = *(const float2*)(S + (size_t)i * 2);
    Xb[i] = pack2(v.x, v.y);
}

// ---------------- SPMM bf16 gather, 4-wide unroll, fused S accumulate ------
// 192 threads = 2 nodes x 96 lanes; each lane owns a bf16 pair (uint).
__global__ __launch_bounds__(192) void k_spmm_bf(const unsigned int* __restrict__ Xb,
                                                 unsigned int* __restrict__ Yb,
                                                 float* __restrict__ S,
                                                 const int* __restrict__ offs,
                                                 const int* __restrict__ deg,
                                                 const int* __restrict__ edst,
                                                 const float* __restrict__ eval) {
    int t = threadIdx.x;
    int half = (t >= FH) ? 1 : 0;
    int c = t - half * FH;
    int n = blockIdx.x * 2 + half;
    int start = offs[n];
    int dg = deg[n];
    const int* ed = edst + start;
    const float* ev = eval + start;
    float a0 = 0.f, a1 = 0.f;
    for (int j = 0; j < dg; j += 4) {
        int last = dg - 1;
        int j1 = (j + 1 < dg) ? j + 1 : last;
        int j2 = (j + 2 < dg) ? j + 2 : last;
        int j3 = (j + 3 < dg) ? j + 3 : last;
        int d0 = ed[j], d1 = ed[j1], d2 = ed[j2], d3 = ed[j3];
        float v0 = ev[j];
        float v1 = (j + 1 < dg) ? ev[j1] : 0.f;
        float v2 = (j + 2 < dg) ? ev[j2] : 0.f;
        float v3 = (j + 3 < dg) ? ev[j3] : 0.f;
        unsigned int x0 = Xb[(size_t)d0 * FH + c];
        unsigned int x1 = Xb[(size_t)d1 * FH + c];
        unsigned int x2 = Xb[(size_t)d2 * FH + c];
        unsigned int x3 = Xb[(size_t)d3 * FH + c];
        a0 = fmaf(v0, bf_lo(x0), a0); a1 = fmaf(v0, bf_hi(x0), a1);
        a0 = fmaf(v1, bf_lo(x1), a0); a1 = fmaf(v1, bf_hi(x1), a1);
        a0 = fmaf(v2, bf_lo(x2), a0); a1 = fmaf(v2, bf_hi(x2), a1);
        a0 = fmaf(v3, bf_lo(x3), a0); a1 = fmaf(v3, bf_hi(x3), a1);
    }
    size_t o = (size_t)n * FH + c;
    Yb[o] = pack2(a0, a1);
    float2* Sp = (float2*)(S + (size_t)n * FF);
    float2 s = Sp[c];
    s.x += a0; s.y += a1;
    Sp[c] = s;
}

// ---------------- attention MLP + readout (8 nodes/block) ----------------
__global__ __launch_bounds__(128) void k_attn(
    const float* __restrict__ S,
    const float* __restrict__ Wu1, const float* __restrict__ bu1,
    const float* __restrict__ Wu2, const float* __restrict__ bu2,
    const float* __restrict__ Wi1, const float* __restrict__ bi1,
    const float* __restrict__ Wi2, const float* __restrict__ bi2,
    float* __restrict__ out) {
    const int NPB = 8;
    int blk = blockIdx.x;
    int node0;
    const float *W1, *B1, *W2, *B2;
    if (blk < N_USERS / NPB) {
        node0 = blk * NPB;
        W1 = Wu1; B1 = bu1; W2 = Wu2; B2 = bu2;
    } else {
        node0 = N_USERS + (blk - N_USERS / NPB) * NPB;
        W1 = Wi1; B1 = bi1; W2 = Wi2; B2 = bi2;
    }
    int t = threadIdx.x;
    __shared__ float hl[NPB][FF];
    __shared__ float hid[NPB][128];
    __shared__ float lg[NPB][3];
    __shared__ float aw[NPB][3];

    const float inv3 = 1.f / 3.f;
#pragma unroll
    for (int q = 0; q < 12; q++) {
        int flat = q * 128 + t;
        int m = flat / FF;
        int r = flat - m * FF;
        hl[m][r] = S[(size_t)(node0 + m) * FF + r] * inv3;
    }
    __syncthreads();

    {
        float accm[NPB];
        float bb = B1[t];
#pragma unroll
        for (int m = 0; m < NPB; m++) accm[m] = bb;
        for (int k = 0; k < FF; k += 4) {
            float w0 = W1[(k + 0) * 128 + t];
            float w1 = W1[(k + 1) * 128 + t];
            float w2 = W1[(k + 2) * 128 + t];
            float w3 = W1[(k + 3) * 128 + t];
#pragma unroll
            for (int m = 0; m < NPB; m++) {
                float4 x = *(float4*)(&hl[m][k]);
                accm[m] = fmaf(x.x, w0, fmaf(x.y, w1, fmaf(x.z, w2, fmaf(x.w, w3, accm[m]))));
            }
        }
#pragma unroll
        for (int m = 0; m < NPB; m++) hid[m][t] = fmaxf(accm[m], 0.f);
    }
    __syncthreads();

    if (t < NPB * 3) {
        int m = t / 3, c = t - m * 3;
        float s = B2[c];
        for (int j = 0; j < 128; j++) s = fmaf(hid[m][j], W2[j * 3 + c], s);
        lg[m][c] = s;
    }
    __syncthreads();

    if (t < NPB) {
        float l0 = lg[t][0], l1 = lg[t][1], l2 = lg[t][2];
        float mx = fmaxf(l0, fmaxf(l1, l2));
        float e0 = expf(l0 - mx), e1 = expf(l1 - mx), e2 = expf(l2 - mx);
        float inv = 1.f / (e0 + e1 + e2);
        aw[t][0] = e0 * inv; aw[t][1] = e1 * inv; aw[t][2] = e2 * inv;
    }
    __syncthreads();

#pragma unroll
    for (int q = 0; q < 4; q++) {
        int flat = q * 128 + t;
        int m = flat >> 6, d = flat & 63;
        out[(size_t)(node0 + m) * DD + d] =
            aw[m][0] * hl[m][d] + aw[m][1] * hl[m][64 + d] + aw[m][2] * hl[m][128 + d];
    }
}

// ---------------- launch ----------------
extern "C" void kernel_launch(void* const* d_in, const int* in_sizes, int n_in,
                              void* d_out, int out_size, void* d_ws, size_t ws_size,
                              hipStream_t stream) {
    (void)in_sizes; (void)n_in; (void)out_size; (void)ws_size;
    const float* x_txt    = (const float*)d_in[0];
    const float* x_img    = (const float*)d_in[1];
    const float* x_struct = (const float*)d_in[2];
    const float* user_emb = (const float*)d_in[3];
    const float* W_txt    = (const float*)d_in[4];
    const float* b_txt    = (const float*)d_in[5];
    const float* W_img    = (const float*)d_in[6];
    const float* b_img    = (const float*)d_in[7];
    const float* W_st     = (const float*)d_in[8];
    const float* b_st     = (const float*)d_in[9];
    const float* Wu1      = (const float*)d_in[10];
    const float* bu1      = (const float*)d_in[11];
    const float* Wu2      = (const float*)d_in[12];
    const float* bu2      = (const float*)d_in[13];
    const float* Wi1      = (const float*)d_in[14];
    const float* bi1      = (const float*)d_in[15];
    const float* Wi2      = (const float*)d_in[16];
    const float* bi2      = (const float*)d_in[17];
    const int*   ei       = (const int*)d_in[18];
    float* out = (float*)d_out;

    char* base = (char*)d_ws;
    size_t off = 0;
    auto take = [&](size_t bytes) -> void* {
        void* p = base + off;
        off += (bytes + 255) & ~(size_t)255;
        return p;
    };
    float* S           = (float*)take((size_t)N_NODES * FF * 4);
    unsigned int* Xb0  = (unsigned int*)take((size_t)N_NODES * FH * 4);
    unsigned int* Yb   = (unsigned int*)take((size_t)N_NODES * FH * 4);
    int* deg    = (int*)take((size_t)N_NODES * 4);
    int* offs   = (int*)take((size_t)SCAN_NBLK * 1024 * 4);
    int* cursor = (int*)take((size_t)N_NODES * 4);
    int* bsum   = (int*)take((size_t)SCAN_NBLK * 4);
    int* bscan  = (int*)take((size_t)SCAN_NBLK * 4);
    float* rsq  = (float*)take((size_t)N_NODES * 4);
    int* edst   = (int*)take((size_t)E_DIR * 4);
    float* eval = (float*)take((size_t)E_DIR * 4);
    int* mode   = (int*)take(256);
    unsigned short* Wtb = (unsigned short*)take((size_t)FF * KK_TOT * 2);

    hipMemsetAsync(deg, 0, (size_t)N_NODES * 4, stream);

    k_mode<<<1, 256, 0, stream>>>(ei, mode);
    k_deg<<<(E_UND + 255) / 256, 256, 0, stream>>>(ei, mode, deg);
    k_scan1<<<SCAN_NBLK, 1024, 0, stream>>>(deg, offs, bsum);
    k_scan2<<<1, 64, 0, stream>>>(bsum, bscan);
    k_scan3<<<(N_NODES + 255) / 256, 256, 0, stream>>>(deg, offs, bscan, cursor, rsq);
    k_fill<<<(E_DIR + 255) / 256, 256, 0, stream>>>(ei, mode, cursor, rsq, edst, eval);

    k_users<<<(N_USERS * FF + 255) / 256, 256, 0, stream>>>(user_emb, S);
    k_cvt_w<<<(FF * KK_TOT + 255) / 256, 256, 0, stream>>>(W_txt, W_img, W_st, Wtb);
    k_item_gemm_mfma<<<dim3((N_ITEMS + BM - 1) / BM, 3), 256, 0, stream>>>(
        x_txt, x_img, x_struct, Wtb, b_txt, b_img, b_st, S);

    k_pack<<<(N_NODES * FH + 255) / 256, 256, 0, stream>>>(S, Xb0);
    k_spmm_bf<<<N_NODES / 2, 192, 0, stream>>>(Xb0, Yb, S, offs, deg, edst, eval);
    k_spmm_bf<<<N_NODES / 2, 192, 0, stream>>>(Yb, Xb0, S, offs, deg, edst, eval);

    k_attn<<<N_NODES / 8, 128, 0, stream>>>(S, Wu1, bu1, Wu2, bu2, Wi1, bi1, Wi2, bi2, out);
}

// Round 4
// 684.471 us; speedup vs baseline: 2.0005x; 1.1516x over previous
//
#include <hip/hip_runtime.h>
#include <math.h>

#define N_USERS 60000
#define N_ITEMS 30000
#define N_NODES 90000
#define DD 64
#define FF 192              // 3*DD
#define FH 96               // FF/2 (bf16 pairs per row)
#define KK_TOT 1408         // 768 + 512 + 128
#define E_UND 500000
#define E_DIR 1000000
#define SCAN_NBLK 88        // ceil(90000/1024)

typedef __attribute__((ext_vector_type(8))) __bf16 bf16x8;
typedef __attribute__((ext_vector_type(8))) unsigned short u16x8;
typedef __attribute__((ext_vector_type(4))) float f32x4;

__device__ __forceinline__ unsigned short f2bf(float f) {
    unsigned int u = __float_as_uint(f);
    unsigned int r = (u + 0x7FFFu + ((u >> 16) & 1u)) >> 16;   // RNE
    return (unsigned short)r;
}
__device__ __forceinline__ float bf_lo(unsigned int x) { return __uint_as_float(x << 16); }
__device__ __forceinline__ float bf_hi(unsigned int x) { return __uint_as_float(x & 0xFFFF0000u); }
__device__ __forceinline__ float bf2f(unsigned short x) {
    return __uint_as_float((unsigned int)x << 16);
}
__device__ __forceinline__ unsigned int pack2(float a, float b) {
    return ((unsigned int)f2bf(b) << 16) | (unsigned int)f2bf(a);
}

// ---------------- edge-layout probe: int32 vs int64 storage ----------------
__global__ void k_mode(const int* __restrict__ ei, int* __restrict__ mode) {
    __shared__ int any;
    if (threadIdx.x == 0) any = 0;
    __syncthreads();
    if (ei[2 * threadIdx.x + 1] != 0) atomicOr(&any, 1);
    __syncthreads();
    if (threadIdx.x == 0) mode[0] = (any == 0) ? 1 : 0;   // 1 => int64 layout
}

__device__ __forceinline__ void load_pair(const int* __restrict__ ei, int md, int u,
                                          int& a, int& b) {
    if (md) { a = ei[2 * u]; b = ei[2 * (E_UND + u)]; }
    else    { a = ei[u];     b = ei[E_UND + u]; }
}

// ---------------- degree count ----------------
__global__ void k_deg(const int* __restrict__ ei, const int* __restrict__ mode,
                      int* __restrict__ deg) {
    int i = blockIdx.x * 256 + threadIdx.x;
    if (i >= E_UND) return;
    int md = mode[0];
    int a, b;
    load_pair(ei, md, i, a, b);
    atomicAdd(&deg[a], 1);
    atomicAdd(&deg[b], 1);
}

// ---------------- exclusive scan (3 kernels) ----------------
__global__ __launch_bounds__(1024) void k_scan1(const int* __restrict__ deg,
                                                int* __restrict__ offs,
                                                int* __restrict__ bsum) {
    __shared__ int tmp[1024];
    int b = blockIdx.x, t = threadIdx.x;
    int i = b * 1024 + t;
    int v = (i < N_NODES) ? deg[i] : 0;
    tmp[t] = v;
    __syncthreads();
    for (int off = 1; off < 1024; off <<= 1) {
        int add = (t >= off) ? tmp[t - off] : 0;
        __syncthreads();
        tmp[t] += add;
        __syncthreads();
    }
    offs[i] = tmp[t] - v;              // exclusive within block
    if (t == 1023) bsum[b] = tmp[t];
}

__global__ void k_scan2(const int* __restrict__ bsum, int* __restrict__ bscan) {
    if (threadIdx.x == 0) {
        int run = 0;
        for (int b = 0; b < SCAN_NBLK; b++) { bscan[b] = run; run += bsum[b]; }
    }
}

__global__ void k_scan3(const int* __restrict__ deg, int* __restrict__ offs,
                        const int* __restrict__ bscan, int* __restrict__ cursor,
                        float* __restrict__ rsq) {
    int i = blockIdx.x * 256 + threadIdx.x;
    if (i >= N_NODES) return;
    int o = offs[i] + bscan[i >> 10];
    offs[i] = o;
    cursor[i] = o;
    int dg = deg[i];
    if (dg < 1) dg = 1;
    rsq[i] = rsqrtf((float)dg);
}

// ---------------- CSR fill (counting-sort scatter) ----------------
__global__ void k_fill(const int* __restrict__ ei, const int* __restrict__ mode,
                       int* __restrict__ cursor, const float* __restrict__ rsq,
                       int* __restrict__ edst, float* __restrict__ eval) {
    int i = blockIdx.x * 256 + threadIdx.x;
    if (i >= E_DIR) return;
    int md = mode[0];
    int u = (i < E_UND) ? i : i - E_UND;
    int a, b;
    load_pair(ei, md, u, a, b);
    int s, d;
    if (i < E_UND) { s = a; d = b; } else { s = b; d = a; }
    int slot = atomicAdd(&cursor[s], 1);
    edst[slot] = d;
    eval[slot] = rsq[s] * rsq[d];
}

// ---------------- user rows: transpose copy into S ----------------
__global__ void k_users(const float* __restrict__ ue, float* __restrict__ S) {
    int idx = blockIdx.x * 256 + threadIdx.x;
    if (idx >= N_USERS * FF) return;
    int n = idx / FF;
    int r = idx - n * FF;
    int b = r >> 6, d = r & 63;
    S[idx] = ue[((size_t)b * N_USERS + n) * DD + d];
}

// ---------------- W transpose+concat+bf16: Wtb[n][k], n=b*64+d ----------------
__global__ void k_cvt_w(const float* __restrict__ Wt, const float* __restrict__ Wi,
                        const float* __restrict__ Wst, unsigned short* __restrict__ Wtb) {
    int idx = blockIdx.x * 256 + threadIdx.x;
    if (idx >= FF * KK_TOT) return;
    int n = idx / KK_TOT;
    int k = idx - n * KK_TOT;
    int b = n >> 6, d = n & 63;
    float v;
    if (k < 768)       v = Wt [((size_t)b * 768 + k) * 64 + d];
    else if (k < 1280) v = Wi [((size_t)b * 512 + (k - 768)) * 64 + d];
    else               v = Wst[((size_t)b * 128 + (k - 1280)) * 64 + d];
    Wtb[idx] = f2bf(v);
}

// ---------------- W1 transpose to bf16: W1T[n][k] = W1[k][n], 128x192 -------
__global__ void k_cvt_w1(const float* __restrict__ Wu1, const float* __restrict__ Wi1,
                         unsigned short* __restrict__ W1Tu,
                         unsigned short* __restrict__ W1Ti) {
    int idx = blockIdx.x * 256 + threadIdx.x;
    if (idx >= 128 * FF) return;
    int n = idx / FF;
    int k = idx - n * FF;
    W1Tu[idx] = f2bf(Wu1[(size_t)k * 128 + n]);
    W1Ti[idx] = f2bf(Wi1[(size_t)k * 128 + n]);
}

// ---------------- item feature GEMM: bf16 MFMA, M=30000 N=192 K=1408 -------
#define BM 128
#define BN 64
#define BK 64
#define LDK 72   // padded LDS pitch (elements)

__global__ __launch_bounds__(256) void k_item_gemm_mfma(
    const float* __restrict__ xt, const float* __restrict__ xi, const float* __restrict__ xs,
    const unsigned short* __restrict__ Wtb,
    const float* __restrict__ bt, const float* __restrict__ bi, const float* __restrict__ bst,
    float* __restrict__ S) {
    __shared__ unsigned short Ash[BM * LDK];
    __shared__ unsigned short Bsh[BN * LDK];
    const int tid  = threadIdx.x;
    const int wave = tid >> 6;
    const int lane = tid & 63;
    const int row0 = blockIdx.x * BM;
    const int n0   = blockIdx.y * BN;     // head b = blockIdx.y

    f32x4 acc[2][4];
#pragma unroll
    for (int tm = 0; tm < 2; tm++)
#pragma unroll
        for (int tn = 0; tn < 4; tn++) acc[tm][tn] = (f32x4){0.f, 0.f, 0.f, 0.f};

    for (int k0 = 0; k0 < KK_TOT; k0 += BK) {
#pragma unroll
        for (int i = 0; i < 4; i++) {
            int id = tid + i * 256;
            int r = id >> 3;
            int c = (id & 7) << 3;
            int gr = row0 + r;
            int gk = k0 + c;
            float4 v0 = make_float4(0.f, 0.f, 0.f, 0.f);
            float4 v1 = v0;
            if (gr < N_ITEMS) {
                const float* src;
                int kl;
                if (gk < 768)       { src = xt + (size_t)gr * 768; kl = gk; }
                else if (gk < 1280) { src = xi + (size_t)gr * 512; kl = gk - 768; }
                else                { src = xs + (size_t)gr * 128; kl = gk - 1280; }
                v0 = *(const float4*)(src + kl);
                v1 = *(const float4*)(src + kl + 4);
            }
            u16x8 pk;
            pk[0] = f2bf(v0.x); pk[1] = f2bf(v0.y); pk[2] = f2bf(v0.z); pk[3] = f2bf(v0.w);
            pk[4] = f2bf(v1.x); pk[5] = f2bf(v1.y); pk[6] = f2bf(v1.z); pk[7] = f2bf(v1.w);
            *(u16x8*)(&Ash[r * LDK + c]) = pk;
        }
#pragma unroll
        for (int i = 0; i < 2; i++) {
            int id = tid + i * 256;
            int r = id >> 3;
            int c = (id & 7) << 3;
            *(u16x8*)(&Bsh[r * LDK + c]) =
                *(const u16x8*)(&Wtb[(size_t)(n0 + r) * KK_TOT + k0 + c]);
        }
        __syncthreads();
#pragma unroll
        for (int kk = 0; kk < BK; kk += 32) {
            bf16x8 af[2], bfr[4];
#pragma unroll
            for (int tm = 0; tm < 2; tm++)
                af[tm] = *(const bf16x8*)(&Ash[(wave * 32 + tm * 16 + (lane & 15)) * LDK +
                                               kk + (lane >> 4) * 8]);
#pragma unroll
            for (int tn = 0; tn < 4; tn++)
                bfr[tn] = *(const bf16x8*)(&Bsh[(tn * 16 + (lane & 15)) * LDK +
                                                kk + (lane >> 4) * 8]);
#pragma unroll
            for (int tm = 0; tm < 2; tm++)
#pragma unroll
                for (int tn = 0; tn < 4; tn++)
                    acc[tm][tn] = __builtin_amdgcn_mfma_f32_16x16x32_bf16(
                        af[tm], bfr[tn], acc[tm][tn], 0, 0, 0);
        }
        __syncthreads();
    }

    const int col16 = lane & 15;
    const int quad  = lane >> 4;
    const int b = blockIdx.y;
#pragma unroll
    for (int tn = 0; tn < 4; tn++) {
        int d = tn * 16 + col16;
        int n = n0 + d;
        float bias = bt[b * 64 + d] + bi[b * 64 + d] + bst[b * 64 + d];
#pragma unroll
        for (int tm = 0; tm < 2; tm++) {
#pragma unroll
            for (int r = 0; r < 4; r++) {
                int row = row0 + wave * 32 + tm * 16 + quad * 4 + r;
                if (row < N_ITEMS) {
                    S[(size_t)(N_USERS + row) * FF + n] = acc[tm][tn][r] + bias;
                }
            }
        }
    }
}

// ---------------- pack fp32 S -> bf16-pair rows ----------------
__global__ void k_pack(const float* __restrict__ S, unsigned int* __restrict__ Xb) {
    int i = blockIdx.x * 256 + threadIdx.x;
    if (i >= N_NODES * FH) return;
    float2 v = *(const float2*)(S + (size_t)i * 2);
    Xb[i] = pack2(v.x, v.y);
}

// ---------------- SPMM bf16 gather, 4-wide unroll, fused S accumulate ------
__global__ __launch_bounds__(192) void k_spmm_bf(const unsigned int* __restrict__ Xb,
                                                 unsigned int* __restrict__ Yb,
                                                 float* __restrict__ S,
                                                 const int* __restrict__ offs,
                                                 const int* __restrict__ deg,
                                                 const int* __restrict__ edst,
                                                 const float* __restrict__ eval) {
    int t = threadIdx.x;
    int half = (t >= FH) ? 1 : 0;
    int c = t - half * FH;
    int n = blockIdx.x * 2 + half;
    int start = offs[n];
    int dg = deg[n];
    const int* ed = edst + start;
    const float* ev = eval + start;
    float a0 = 0.f, a1 = 0.f;
    for (int j = 0; j < dg; j += 4) {
        int last = dg - 1;
        int j1 = (j + 1 < dg) ? j + 1 : last;
        int j2 = (j + 2 < dg) ? j + 2 : last;
        int j3 = (j + 3 < dg) ? j + 3 : last;
        int d0 = ed[j], d1 = ed[j1], d2 = ed[j2], d3 = ed[j3];
        float v0 = ev[j];
        float v1 = (j + 1 < dg) ? ev[j1] : 0.f;
        float v2 = (j + 2 < dg) ? ev[j2] : 0.f;
        float v3 = (j + 3 < dg) ? ev[j3] : 0.f;
        unsigned int x0 = Xb[(size_t)d0 * FH + c];
        unsigned int x1 = Xb[(size_t)d1 * FH + c];
        unsigned int x2 = Xb[(size_t)d2 * FH + c];
        unsigned int x3 = Xb[(size_t)d3 * FH + c];
        a0 = fmaf(v0, bf_lo(x0), a0); a1 = fmaf(v0, bf_hi(x0), a1);
        a0 = fmaf(v1, bf_lo(x1), a0); a1 = fmaf(v1, bf_hi(x1), a1);
        a0 = fmaf(v2, bf_lo(x2), a0); a1 = fmaf(v2, bf_hi(x2), a1);
        a0 = fmaf(v3, bf_lo(x3), a0); a1 = fmaf(v3, bf_hi(x3), a1);
    }
    size_t o = (size_t)n * FH + c;
    Yb[o] = pack2(a0, a1);
    float2* Sp = (float2*)(S + (size_t)n * FF);
    float2 s = Sp[c];
    s.x += a0; s.y += a1;
    Sp[c] = s;
}

// ---------------- attention: MFMA MLP + softmax + readout ------------------
// Block = 256 threads (4 waves), 64 node rows. A = bf16(S/3) in LDS (pitch 200).
// GEMM1: H = relu(A @ W1T^T) per wave: 16 rows x 128 cols.
// Logits from C-frags + shfl_xor butterfly; softmax in regs; readout from LDS.
#define LDA 200

__global__ __launch_bounds__(256) void k_attn_mfma(
    const float* __restrict__ S,
    const unsigned short* __restrict__ W1T,   // 128 x 192 bf16 (pre-transposed)
    const float* __restrict__ B1,             // 128
    const float* __restrict__ W2,             // 128 x 3
    const float* __restrict__ B2,             // 3
    float* __restrict__ out,
    int node_base, int n_rows) {
    __shared__ unsigned short Atile[64 * LDA];
    __shared__ float aws[64][4];
    const int tid  = threadIdx.x;
    const int wave = tid >> 6;
    const int lane = tid & 63;
    const int row0 = blockIdx.x * 64;
    const float inv3 = 1.f / 3.f;

    // stage A: 64 rows x 192 cols, fp32 S -> bf16(S/3); 1536 chunks of 8
#pragma unroll
    for (int i = 0; i < 6; i++) {
        int id = tid + i * 256;
        int r = id / 24;
        int c = (id - r * 24) * 8;
        u16x8 pk;
        if (row0 + r < n_rows) {
            const float* src = S + (size_t)(node_base + row0 + r) * FF + c;
            float4 v0 = *(const float4*)(src);
            float4 v1 = *(const float4*)(src + 4);
            pk[0] = f2bf(v0.x * inv3); pk[1] = f2bf(v0.y * inv3);
            pk[2] = f2bf(v0.z * inv3); pk[3] = f2bf(v0.w * inv3);
            pk[4] = f2bf(v1.x * inv3); pk[5] = f2bf(v1.y * inv3);
            pk[6] = f2bf(v1.z * inv3); pk[7] = f2bf(v1.w * inv3);
        } else {
            pk = (u16x8){0, 0, 0, 0, 0, 0, 0, 0};
        }
        *(u16x8*)(&Atile[r * LDA + c]) = pk;
    }
    __syncthreads();

    // GEMM1: wave w handles rows w*16..w*16+15; N=128 as 8 tn tiles
    f32x4 acc[8];
#pragma unroll
    for (int tn = 0; tn < 8; tn++) acc[tn] = (f32x4){0.f, 0.f, 0.f, 0.f};
    const int l16 = lane & 15;
    const int quad = lane >> 4;
#pragma unroll
    for (int kk = 0; kk < FF; kk += 32) {
        bf16x8 af = *(const bf16x8*)(&Atile[(wave * 16 + l16) * LDA + kk + quad * 8]);
#pragma unroll
        for (int tn = 0; tn < 8; tn++) {
            bf16x8 bf = *(const bf16x8*)(&W1T[(size_t)(tn * 16 + l16) * FF + kk + quad * 8]);
            acc[tn] = __builtin_amdgcn_mfma_f32_16x16x32_bf16(af, bf, acc[tn], 0, 0, 0);
        }
    }

    // logits: pl[r][c] = sum over this lane's 8 cols of relu(h+b1)*W2
    float pl[4][3];
#pragma unroll
    for (int r = 0; r < 4; r++) { pl[r][0] = 0.f; pl[r][1] = 0.f; pl[r][2] = 0.f; }
#pragma unroll
    for (int tn = 0; tn < 8; tn++) {
        int col = tn * 16 + l16;
        float b1v = B1[col];
        float w0 = W2[col * 3 + 0], w1 = W2[col * 3 + 1], w2v = W2[col * 3 + 2];
#pragma unroll
        for (int r = 0; r < 4; r++) {
            float h = fmaxf(acc[tn][r] + b1v, 0.f);
            pl[r][0] = fmaf(h, w0, pl[r][0]);
            pl[r][1] = fmaf(h, w1, pl[r][1]);
            pl[r][2] = fmaf(h, w2v, pl[r][2]);
        }
    }
    // butterfly over the 16 lanes sharing the same rows (xor bits 0..3)
#pragma unroll
    for (int m = 1; m <= 8; m <<= 1) {
#pragma unroll
        for (int r = 0; r < 4; r++) {
            pl[r][0] += __shfl_xor(pl[r][0], m, 64);
            pl[r][1] += __shfl_xor(pl[r][1], m, 64);
            pl[r][2] += __shfl_xor(pl[r][2], m, 64);
        }
    }
    float b20 = B2[0], b21 = B2[1], b22 = B2[2];
    if (l16 == 0) {
#pragma unroll
        for (int r = 0; r < 4; r++) {
            float l0 = pl[r][0] + b20, l1 = pl[r][1] + b21, l2 = pl[r][2] + b22;
            float mx = fmaxf(l0, fmaxf(l1, l2));
            float e0 = __expf(l0 - mx), e1 = __expf(l1 - mx), e2 = __expf(l2 - mx);
            float inv = 1.f / (e0 + e1 + e2);
            int rr = wave * 16 + quad * 4 + r;
            aws[rr][0] = e0 * inv; aws[rr][1] = e1 * inv; aws[rr][2] = e2 * inv;
        }
    }
    __syncthreads();

    // readout: out[n][d] = sum_b aw[b] * (S[n][b*64+d]/3), from LDS bf16 tile
#pragma unroll
    for (int i = 0; i < 16; i++) {
        int flat = tid + i * 256;
        int r = flat >> 6, d = flat & 63;
        if (row0 + r < n_rows) {
            float a0 = aws[r][0], a1 = aws[r][1], a2 = aws[r][2];
            const unsigned short* Ar = &Atile[r * LDA];
            float v = a0 * bf2f(Ar[d]) + a1 * bf2f(Ar[64 + d]) + a2 * bf2f(Ar[128 + d]);
            out[(size_t)(node_base + row0 + r) * DD + d] = v;
        }
    }
}

// ---------------- launch ----------------
extern "C" void kernel_launch(void* const* d_in, const int* in_sizes, int n_in,
                              void* d_out, int out_size, void* d_ws, size_t ws_size,
                              hipStream_t stream) {
    (void)in_sizes; (void)n_in; (void)out_size; (void)ws_size;
    const float* x_txt    = (const float*)d_in[0];
    const float* x_img    = (const float*)d_in[1];
    const float* x_struct = (const float*)d_in[2];
    const float* user_emb = (const float*)d_in[3];
    const float* W_txt    = (const float*)d_in[4];
    const float* b_txt    = (const float*)d_in[5];
    const float* W_img    = (const float*)d_in[6];
    const float* b_img    = (const float*)d_in[7];
    const float* W_st     = (const float*)d_in[8];
    const float* b_st     = (const float*)d_in[9];
    const float* Wu1      = (const float*)d_in[10];
    const float* bu1      = (const float*)d_in[11];
    const float* Wu2      = (const float*)d_in[12];
    const float* bu2      = (const float*)d_in[13];
    const float* Wi1      = (const float*)d_in[14];
    const float* bi1      = (const float*)d_in[15];
    const float* Wi2      = (const float*)d_in[16];
    const float* bi2      = (const float*)d_in[17];
    const int*   ei       = (const int*)d_in[18];
    float* out = (float*)d_out;

    char* base = (char*)d_ws;
    size_t off = 0;
    auto take = [&](size_t bytes) -> void* {
        void* p = base + off;
        off += (bytes + 255) & ~(size_t)255;
        return p;
    };
    float* S           = (float*)take((size_t)N_NODES * FF * 4);
    unsigned int* Xb0  = (unsigned int*)take((size_t)N_NODES * FH * 4);
    unsigned int* Yb   = (unsigned int*)take((size_t)N_NODES * FH * 4);
    int* deg    = (int*)take((size_t)N_NODES * 4);
    int* offs   = (int*)take((size_t)SCAN_NBLK * 1024 * 4);
    int* cursor = (int*)take((size_t)N_NODES * 4);
    int* bsum   = (int*)take((size_t)SCAN_NBLK * 4);
    int* bscan  = (int*)take((size_t)SCAN_NBLK * 4);
    float* rsq  = (float*)take((size_t)N_NODES * 4);
    int* edst   = (int*)take((size_t)E_DIR * 4);
    float* eval = (float*)take((size_t)E_DIR * 4);
    int* mode   = (int*)take(256);
    unsigned short* Wtb  = (unsigned short*)take((size_t)FF * KK_TOT * 2);
    unsigned short* W1Tu = (unsigned short*)take((size_t)128 * FF * 2);
    unsigned short* W1Ti = (unsigned short*)take((size_t)128 * FF * 2);

    hipMemsetAsync(deg, 0, (size_t)N_NODES * 4, stream);

    k_mode<<<1, 256, 0, stream>>>(ei, mode);
    k_deg<<<(E_UND + 255) / 256, 256, 0, stream>>>(ei, mode, deg);
    k_scan1<<<SCAN_NBLK, 1024, 0, stream>>>(deg, offs, bsum);
    k_scan2<<<1, 64, 0, stream>>>(bsum, bscan);
    k_scan3<<<(N_NODES + 255) / 256, 256, 0, stream>>>(deg, offs, bscan, cursor, rsq);
    k_fill<<<(E_DIR + 255) / 256, 256, 0, stream>>>(ei, mode, cursor, rsq, edst, eval);

    k_users<<<(N_USERS * FF + 255) / 256, 256, 0, stream>>>(user_emb, S);
    k_cvt_w<<<(FF * KK_TOT + 255) / 256, 256, 0, stream>>>(W_txt, W_img, W_st, Wtb);
    k_cvt_w1<<<(128 * FF + 255) / 256, 256, 0, stream>>>(Wu1, Wi1, W1Tu, W1Ti);
    k_item_gemm_mfma<<<dim3((N_ITEMS + BM - 1) / BM, 3), 256, 0, stream>>>(
        x_txt, x_img, x_struct, Wtb, b_txt, b_img, b_st, S);

    k_pack<<<(N_NODES * FH + 255) / 256, 256, 0, stream>>>(S, Xb0);
    k_spmm_bf<<<N_NODES / 2, 192, 0, stream>>>(Xb0, Yb, S, offs, deg, edst, eval);
    k_spmm_bf<<<N_NODES / 2, 192, 0, stream>>>(Yb, Xb0, S, offs, deg, edst, eval);

    k_attn_mfma<<<(N_USERS + 63) / 64, 256, 0, stream>>>(
        S, W1Tu, bu1, Wu2, bu2, out, 0, N_USERS);
    k_attn_mfma<<<(N_ITEMS + 63) / 64, 256, 0, stream>>>(
        S, W1Ti, bi1, Wi2, bi2, out, N_USERS, N_ITEMS);
}